// Round 11
// baseline (1889.518 us; speedup 1.0000x reference)
//
#include <hip/hip_runtime.h>
#include <hip/hip_bf16.h>

#define BB 256      // batch
#define TT 2048     // timesteps
#define DD 32       // obs dim
#define HH 64       // hidden
#define GG 256      // 4*H gates
#define ME 16       // batch elements packed per block (= MFMA M)
#define NBLK (BB/ME)
#define CT 8        // timesteps of x staged per chunk
#define NCH (TT/CT)

typedef short bf16x8 __attribute__((ext_vector_type(8)));
typedef float f32x4 __attribute__((ext_vector_type(4)));
typedef unsigned short u16x4 __attribute__((ext_vector_type(4)));

__device__ __forceinline__ float fast_sig(float x) {
    return __builtin_amdgcn_rcpf(1.0f + __expf(-x));
}
// exact split: v ~= hi + lo (both bf16, truncated); residual ~2^-17 rel
__device__ __forceinline__ void split_bf16(float v, unsigned short& hi, unsigned short& lo) {
    unsigned u = __float_as_uint(v);
    hi = (unsigned short)(u >> 16);
    float r = v - __uint_as_float((unsigned)hi << 16);
    lo = (unsigned short)(__float_as_uint(r) >> 16);
}
// LDS-only barrier: drain lgkmcnt, leave global loads/stores in flight.
__device__ __forceinline__ void lds_barrier() {
    asm volatile("s_waitcnt lgkmcnt(0)" ::: "memory");
    __builtin_amdgcn_s_barrier();
    asm volatile("" ::: "memory");
}

// 16 batch elements per block; gates[16,256] = [x|h][16,96] @ W[96,256] via
// bf16 hi/lo-split MFMA (3 terms). Wave w owns N-tiles {w,4+w,8+w,12+w} so
// unit u's i,f,g,o accumulate in the SAME lane -> lane-local update.
// h republished per step as pre-split hi/lo u16 LDS arrays; A-frags read
// back as direct ds_read_b128. One lgkm-only barrier per step.
__global__ __launch_bounds__(256, 1) void lstm_mfma_kernel(
    const float* __restrict__ y,    // [B, T, D]
    const float* __restrict__ Wx,   // [D, 4H]
    const float* __restrict__ Wh,   // [H, 4H]
    const float* __restrict__ b,    // [4H]
    float* __restrict__ out)        // [B, T, H]
{
    const int tid = threadIdx.x;
    const int w = tid >> 6;          // wave id 0..3 (unit block)
    const int l = tid & 63;
    const int eps = l & 15;          // A-row / B-col lane coord
    const int q = l >> 4;            // k-group lane coord

    __shared__ unsigned short h_hi[2][ME][80];        // stride 80 u16 = 160 B
    __shared__ unsigned short h_lo[2][ME][80];
    __shared__ unsigned short x_hi[2][CT][ME][40];    // stride 40 u16 = 80 B
    __shared__ unsigned short x_lo[2][CT][ME][40];

    // ---- B fragments (hi/lo bf16), loaded once. W[k][n]: k<32 -> Wx, else Wh.
    // (lane,slot)->k map identical for A and B => k-permutation errors cancel.
    bf16x8 bh[4][3], bl[4][3];
#pragma unroll
    for (int g = 0; g < 4; ++g) {
        const int n = 64 * g + 16 * w + eps;
#pragma unroll
        for (int kc = 0; kc < 3; ++kc) {
#pragma unroll
            for (int s = 0; s < 8; ++s) {
                const int k = 32 * kc + 8 * q + s;
                float v = (k < DD) ? Wx[k * GG + n] : Wh[(k - DD) * GG + n];
                unsigned short hi_, lo_;
                split_bf16(v, hi_, lo_);
                bh[g][kc][s] = (short)hi_;
                bl[g][kc][s] = (short)lo_;
            }
        }
    }
    float bias[4];
#pragma unroll
    for (int g = 0; g < 4; ++g) bias[g] = b[64 * g + 16 * w + eps];

    float cr[4] = {0.0f, 0.0f, 0.0f, 0.0f};   // c for elements e=4q+r, unit 16w+eps

    // zero h buffers (h0 = 0)
    for (int i = tid; i < 2 * ME * 80; i += 256) {
        ((unsigned short*)h_hi)[i] = 0;
        ((unsigned short*)h_lo)[i] = 0;
    }

    // ---- x staging: thread -> (element se, step st_, half sh); 4 float4 each
    const int se = tid >> 4, st_ = (tid >> 1) & 7, sh = tid & 1;
    const float* yb = y + ((size_t)(blockIdx.x * ME + se) * TT) * DD + sh * 16;
    float* ob = out + (size_t)(blockIdx.x * ME) * TT * HH;

    float4 pf[4];
#define ISSUE(CC) { const float* p_ = yb + (size_t)((CC) * CT + st_) * DD;     \
    _Pragma("unroll") for (int i_ = 0; i_ < 4; ++i_) pf[i_] = ((const float4*)p_)[i_]; }
#define COMMIT(CB) { _Pragma("unroll") for (int i_ = 0; i_ < 4; ++i_) {        \
        unsigned short h0,h1,h2,h3,l0,l1,l2,l3;                                \
        split_bf16(pf[i_].x, h0, l0); split_bf16(pf[i_].y, h1, l1);            \
        split_bf16(pf[i_].z, h2, l2); split_bf16(pf[i_].w, h3, l3);            \
        u16x4 vh_ = {h0,h1,h2,h3}, vl_ = {l0,l1,l2,l3};                        \
        *(u16x4*)&x_hi[CB][st_][se][sh*16 + i_*4] = vh_;                       \
        *(u16x4*)&x_lo[CB][st_][se][sh*16 + i_*4] = vl_;                       \
    } }

#define MFMA(A, B_, C_) __builtin_amdgcn_mfma_f32_16x16x32_bf16((A), (B_), (C_), 0, 0, 0)

#define STEPM(CB, TL, RD) {                                                    \
    bf16x8 ah0 = *(const bf16x8*)&x_hi[CB][TL][eps][8*q];                      \
    bf16x8 al0 = *(const bf16x8*)&x_lo[CB][TL][eps][8*q];                      \
    bf16x8 ah1 = *(const bf16x8*)&h_hi[RD][eps][8*q];                          \
    bf16x8 al1 = *(const bf16x8*)&h_lo[RD][eps][8*q];                          \
    bf16x8 ah2 = *(const bf16x8*)&h_hi[RD][eps][32 + 8*q];                     \
    bf16x8 al2 = *(const bf16x8*)&h_lo[RD][eps][32 + 8*q];                     \
    f32x4 acc[4];                                                              \
    _Pragma("unroll")                                                          \
    for (int g = 0; g < 4; ++g) {                                              \
        acc[g] = (f32x4){0.0f, 0.0f, 0.0f, 0.0f};                              \
        acc[g] = MFMA(al0, bh[g][0], acc[g]);                                  \
        acc[g] = MFMA(ah0, bl[g][0], acc[g]);                                  \
        acc[g] = MFMA(ah0, bh[g][0], acc[g]);                                  \
        acc[g] = MFMA(al1, bh[g][1], acc[g]);                                  \
        acc[g] = MFMA(ah1, bl[g][1], acc[g]);                                  \
        acc[g] = MFMA(ah1, bh[g][1], acc[g]);                                  \
        acc[g] = MFMA(al2, bh[g][2], acc[g]);                                  \
        acc[g] = MFMA(ah2, bl[g][2], acc[g]);                                  \
        acc[g] = MFMA(ah2, bh[g][2], acc[g]);                                  \
    }                                                                          \
    _Pragma("unroll")                                                          \
    for (int r = 0; r < 4; ++r) {                                              \
        float gi = acc[0][r] + bias[0], gf = acc[1][r] + bias[1];              \
        float gg = acc[2][r] + bias[2], go = acc[3][r] + bias[3];              \
        float i_ = fast_sig(gi), f_ = fast_sig(gf), o_ = fast_sig(go);         \
        float g_ = fmaf(2.0f, fast_sig(2.0f * gg), -1.0f);                     \
        cr[r] = fmaf(f_, cr[r], i_ * g_);                                      \
        float h_ = o_ * fmaf(2.0f, fast_sig(2.0f * cr[r]), -1.0f);             \
        unsigned short hh_, hl_;                                               \
        split_bf16(h_, hh_, hl_);                                              \
        const int e_ = 4 * q + r;                                              \
        h_hi[(RD) ^ 1][e_][16 * w + eps] = hh_;                                \
        h_lo[(RD) ^ 1][e_][16 * w + eps] = hl_;                                \
        ob[((size_t)e_ * TT + (c * CT + (TL))) * HH + 16 * w + eps] = h_;      \
    }                                                                          \
    lds_barrier(); }

    // prologue: chunk 0 staged synchronously; chunk 1 issued
    ISSUE(0); COMMIT(0);
    __syncthreads();
    ISSUE(1);

    for (int c = 0; c < NCH; ++c) {
        const int cb = c & 1;
        STEPM(cb, 0, 0) STEPM(cb, 1, 1) STEPM(cb, 2, 0) STEPM(cb, 3, 1)
        STEPM(cb, 4, 0) STEPM(cb, 5, 1) STEPM(cb, 6, 0)
        COMMIT(cb ^ 1);                       // write chunk c+1 (loads long done)
        STEPM(cb, 7, 1)                       // its barrier publishes xs to all waves
        { const int cn = (c + 2 < NCH) ? (c + 2) : (NCH - 1); ISSUE(cn); }
    }
#undef STEPM
#undef MFMA
#undef COMMIT
#undef ISSUE
}

extern "C" void kernel_launch(void* const* d_in, const int* in_sizes, int n_in,
                              void* d_out, int out_size, void* d_ws, size_t ws_size,
                              hipStream_t stream) {
    const float* y  = (const float*)d_in[0];
    const float* Wx = (const float*)d_in[1];
    const float* Wh = (const float*)d_in[2];
    const float* b  = (const float*)d_in[3];
    float* out = (float*)d_out;

    lstm_mfma_kernel<<<NBLK, 256, 0, stream>>>(y, Wx, Wh, b, out);
}